// Round 2
// baseline (335.977 us; speedup 1.0000x reference)
//
#include <hip/hip_runtime.h>
#include <stdint.h>

typedef unsigned short u16;
typedef __bf16 bf16x8 __attribute__((ext_vector_type(8)));
typedef float f32x4 __attribute__((ext_vector_type(4)));

// Sizes
// x:  [16][256][64][64] fp32
// w:  [256][128][4][4]  fp32
// out:[16][128][128][128] fp32
// x_t (ws): [16][66][66][256] bf16, spatially padded by 1 with zeros
// Wk  (ws): [4 classes][128 co][k=tap*256+ci] bf16
static const size_t XT_BYTES = (size_t)16 * 66 * 66 * 256 * 2; // 35,684,352
static const size_t WK_BYTES = (size_t)4 * 128 * 1024 * 2;     //  1,048,576

__device__ __forceinline__ u16 f2bf(float f) {
  unsigned u = __float_as_uint(f);
  unsigned r = (u + 0x7fff + ((u >> 16) & 1)) >> 16; // RNE
  return (u16)r;
}

// async 16B global->LDS
__device__ __forceinline__ void ld_g2l16(const u16* g, void* l) {
  __builtin_amdgcn_global_load_lds(
      (const __attribute__((address_space(1))) unsigned int*)(uintptr_t)g,
      (__attribute__((address_space(3))) unsigned int*)(unsigned int)(uintptr_t)l,
      16, 0, 0);
}

// ---------------- zero-fill x_t (provides all padding borders) ----------------
__global__ __launch_bounds__(256) void zero_xt(uint4* __restrict__ xt) {
  size_t i = (size_t)blockIdx.x * 256 + threadIdx.x;
  if (i < XT_BYTES / 16) xt[i] = make_uint4(0, 0, 0, 0);
}

// ---------------- prep: x fp32 NCHW -> bf16 padded NHWC (interior) ----------------
// block: ih = bx (0..63), ci-half = by (0..1), n = bz
__global__ __launch_bounds__(256) void prep_x(const float* __restrict__ x,
                                              u16* __restrict__ xt) {
  __shared__ __align__(16) u16 shb[128 * 68];  // [ci_local][iw], pitch 68 u16
  __shared__ __align__(16) uint4 sh2[64 * 17]; // [iw][chunk], pitch 17 uint4
  const int t = threadIdx.x;
  const int ih = blockIdx.x, half = blockIdx.y, n = blockIdx.z;
  const int ci0 = half * 128;
  // phase a: coalesced float4 reads, bf16 convert, LDS write (conflict-free)
#pragma unroll
  for (int it = 0; it < 8; ++it) {
    const int cil = it * 16 + (t >> 4);
    const int iw4 = t & 15;
    const float4 v =
        *(const float4*)&x[(((size_t)n * 256 + ci0 + cil) * 64 + ih) * 64 + iw4 * 4];
    ushort4 h;
    h.x = f2bf(v.x); h.y = f2bf(v.y); h.z = f2bf(v.z); h.w = f2bf(v.w);
    *(ushort4*)&shb[cil * 68 + iw4 * 4] = h;
  }
  __syncthreads();
  // phase b: transposed scalar reads (2-way, free), pack uint4, stage in sh2
  {
    const int iw = t & 63;
    const int cq = t >> 6;
#pragma unroll
    for (int j = 0; j < 4; ++j) {
      const int chunk = cq * 4 + j;
      u16 vals[8];
#pragma unroll
      for (int r = 0; r < 8; ++r) vals[r] = shb[(chunk * 8 + r) * 68 + iw];
      uint4 o;
      o.x = (unsigned)vals[0] | ((unsigned)vals[1] << 16);
      o.y = (unsigned)vals[2] | ((unsigned)vals[3] << 16);
      o.z = (unsigned)vals[4] | ((unsigned)vals[5] << 16);
      o.w = (unsigned)vals[6] | ((unsigned)vals[7] << 16);
      sh2[iw * 17 + chunk] = o;
    }
  }
  __syncthreads();
  // phase c: coalesced global writes (256B per 16 lanes)
  u16* dst = xt + (((size_t)n * 66 + ih + 1) * 66 + 1) * 256 + ci0;
#pragma unroll
  for (int j2 = 0; j2 < 4; ++j2) {
    const int idx = j2 * 256 + t;
    const int iw = idx >> 4, chunk = idx & 15;
    uint4 v = sh2[iw * 17 + chunk];
    *(uint4*)&dst[(size_t)iw * 256 + chunk * 8] = v;
  }
}

// ---------------- prep: weights -> per-class k-contiguous bf16 ----------------
__global__ __launch_bounds__(256) void prep_w(const float* __restrict__ w,
                                              u16* __restrict__ wk) {
  int id = blockIdx.x * 256 + threadIdx.x; // < 524288
  int ci = id & 255;
  int tap = (id >> 8) & 3;
  int co = (id >> 10) & 127;
  int cls = id >> 17; // 0..3
  int p = cls >> 1, q = cls & 1;
  int dh = tap >> 1, dw = tap & 1;
  int kh = 2 * dh + 1 - p;
  int kw = 2 * dw + 1 - q;
  wk[id] = f2bf(w[((ci * 128 + co) * 4 + kh) * 4 + kw]);
}

// ---------------- main: per-parity-class implicit GEMM, dbuf pipeline ----------------
// C[co][col] = sum_k Wk[cls][co][k] * B[k][col], k = tap*256+ci = u*32 + (k&31)
__global__ __launch_bounds__(256) void gemm_ct(const u16* __restrict__ xt,
                                               const u16* __restrict__ wk,
                                               const float* __restrict__ bias,
                                               float* __restrict__ out) {
  __shared__ uint4 Ash0[512], Bsh0[512]; // buffer 0: [row 0..127][slot 0..3]
  __shared__ uint4 Ash1[512], Bsh1[512]; // buffer 1
  const int t = threadIdx.x;
  const int lane = t & 63;
  const int wv = t >> 6;
  const int wm = wv >> 1, wn = wv & 1;
  const int quad = lane >> 4, l15 = lane & 15;
  const int mt = blockIdx.x;  // 0..31
  const int n = blockIdx.y;   // 0..15
  const int cls = blockIdx.z; // 0..3
  const int p = cls >> 1, q = cls & 1;
  const int m0 = mt * 2;

  // staging decomposition (row = idx>>2; slot = idx&3; chunk XOR-swizzled)
  const int idx0 = t, idx1 = 256 + t;
  const int ro0 = idx0 >> 2, ch0 = (idx0 & 3) ^ (ro0 & 3);
  const int ro1 = idx1 >> 2, ch1 = (idx1 & 3) ^ (ro1 & 3);
  const u16* wkc = wk + (size_t)cls * 128 * 1024;

  const int mr0 = ro0 >> 6, lB0 = ro0 & 63;
  const int mr1 = ro1 >> 6, lB1 = ro1 & 63;

  // base pointers at (tap=0, s=0)
  const u16* abase0 = wkc + ro0 * 1024 + ch0 * 8;
  const u16* abase1 = wkc + ro1 * 1024 + ch1 * 8;
  const u16* bbase0 =
      xt + (((size_t)n * 66 + (m0 + mr0 + p + 1)) * 66 + (lB0 + q + 1)) * 256 + ch0 * 8;
  const u16* bbase1 =
      xt + (((size_t)n * 66 + (m0 + mr1 + p + 1)) * 66 + (lB1 + q + 1)) * 256 + ch1 * 8;

  // constant frag-read offsets (uint4 index), XOR-swizzled
  int aoff[4], boff[4];
#pragma unroll
  for (int i = 0; i < 4; ++i) {
    int co = wm * 64 + i * 16 + l15;
    aoff[i] = co * 4 + (quad ^ (co & 3));
    int col = wn * 64 + i * 16 + l15;
    boff[i] = col * 4 + (quad ^ (col & 3));
  }

  f32x4 acc[4][4];
#pragma unroll
  for (int i = 0; i < 4; ++i)
#pragma unroll
    for (int j = 0; j < 4; ++j) acc[i][j] = (f32x4){0.f, 0.f, 0.f, 0.f};

  auto issue = [&](int u, uint4* A, uint4* B) {
    const int s = u & 7;
    const int dh = (u >> 4) & 1, dw = (u >> 3) & 1;
    const int bo = s * 32 - (dh * 66 + dw) * 256;
    const int ao = u * 32;
    ld_g2l16(abase0 + ao, &A[idx0]);
    ld_g2l16(abase1 + ao, &A[idx1]);
    ld_g2l16(bbase0 + bo, &B[idx0]);
    ld_g2l16(bbase1 + bo, &B[idx1]);
  };
  auto compute = [&](const uint4* A, const uint4* B) {
    bf16x8 af[4], bfr[4];
#pragma unroll
    for (int i = 0; i < 4; ++i) af[i] = *(const bf16x8*)&A[aoff[i]];
#pragma unroll
    for (int i = 0; i < 4; ++i) bfr[i] = *(const bf16x8*)&B[boff[i]];
#pragma unroll
    for (int i = 0; i < 4; ++i)
#pragma unroll
      for (int j = 0; j < 4; ++j)
        acc[i][j] =
            __builtin_amdgcn_mfma_f32_16x16x32_bf16(af[i], bfr[j], acc[i][j], 0, 0, 0);
  };

  issue(0, Ash0, Bsh0);
  for (int uu = 0; uu < 32; uu += 2) {
    __syncthreads(); // drains loads for stage uu (vmcnt(0)); ends reads of buf1
    issue(uu + 1, Ash1, Bsh1); // prefetch next stage (uu+1 <= 31 always)
    compute(Ash0, Bsh0);
    __syncthreads(); // drains loads for stage uu+1; ends reads of buf0
    if (uu + 2 < 32) issue(uu + 2, Ash0, Bsh0);
    compute(Ash1, Bsh1);
  }

  // epilogue: C/D layout col=lane&15, row=quad*4+reg
  const int oh = 2 * (m0 + wn) + p;
#pragma unroll
  for (int i = 0; i < 4; ++i) {
#pragma unroll
    for (int j = 0; j < 4; ++j) {
      f32x4 v = acc[i][j];
      int l = j * 16 + l15;
      int ow = 2 * l + q;
#pragma unroll
      for (int r = 0; r < 4; ++r) {
        int co = wm * 64 + i * 16 + quad * 4 + r;
        out[(((size_t)n * 128 + co) * 128 + oh) * 128 + ow] = v[r] + bias[co];
      }
    }
  }
}

// ---------------- safety fallback (ws too small): direct fp32 ----------------
__global__ __launch_bounds__(256) void ct_fallback(const float* __restrict__ x,
                                                   const float* __restrict__ w,
                                                   const float* __restrict__ bias,
                                                   float* __restrict__ out) {
  size_t id = (size_t)blockIdx.x * 256 + threadIdx.x;
  if (id >= (size_t)16 * 128 * 128 * 128) return;
  int ow = (int)(id & 127), oh = (int)(id >> 7) & 127;
  int co = (int)(id >> 14) & 127, n = (int)(id >> 21);
  int pp = oh & 1, m = oh >> 1, qq = ow & 1, l = ow >> 1;
  float s = bias[co];
  for (int ci = 0; ci < 256; ++ci) {
    for (int dh = 0; dh < 2; ++dh) {
      int ih = m + pp - dh;
      if (ih < 0 || ih > 63) continue;
      int kh = 2 * dh + 1 - pp;
      for (int dw = 0; dw < 2; ++dw) {
        int iw = l + qq - dw;
        if (iw < 0 || iw > 63) continue;
        int kw = 2 * dw + 1 - qq;
        s += x[(((size_t)n * 256 + ci) * 64 + ih) * 64 + iw] *
             w[((ci * 128 + co) * 4 + kh) * 4 + kw];
      }
    }
  }
  out[id] = s;
}

extern "C" void kernel_launch(void* const* d_in, const int* in_sizes, int n_in,
                              void* d_out, int out_size, void* d_ws, size_t ws_size,
                              hipStream_t stream) {
  const float* x = (const float*)d_in[0];
  const float* w = (const float*)d_in[1];
  const float* bias = (const float*)d_in[2];
  float* out = (float*)d_out;
  if (ws_size >= XT_BYTES + WK_BYTES) {
    u16* xt = (u16*)d_ws;
    u16* wk = (u16*)((char*)d_ws + XT_BYTES);
    hipLaunchKernelGGL(zero_xt, dim3((unsigned)((XT_BYTES / 16 + 255) / 256)), dim3(256),
                       0, stream, (uint4*)xt);
    hipLaunchKernelGGL(prep_w, dim3(2048), dim3(256), 0, stream, w, wk);
    hipLaunchKernelGGL(prep_x, dim3(64, 2, 16), dim3(256), 0, stream, x, xt);
    hipLaunchKernelGGL(gemm_ct, dim3(32, 16, 4), dim3(256), 0, stream, xt, wk, bias, out);
  } else {
    hipLaunchKernelGGL(ct_fallback, dim3(131072), dim3(256), 0, stream, x, w, bias, out);
  }
}